// Round 12
// baseline (311.119 us; speedup 1.0000x reference)
//
#include <hip/hip_runtime.h>

// r26: r25 with the two confounds separated and the one clean lever applied:
//  (a) gather reverted (r25 counters: in1 44us, scattered 16B x-loads);
//      prep = r24's 1900-block embed+pack, in1 reads contiguous h1.
//  (b) kb=4 K-split at M=32 (isolates r23's useful variable): per-wave
//      atom chain 7 -> 3-4, grid/job 256 -> 512 (in-loop 1536 blocks =
//      full 4/CU). Weight traffic unchanged by K-split; partials 2 -> 4
//      (gates/head use r23's proven 4-partial sum).
//  (c) head-absorbed gates2(6), loss_fin, launch_bounds(256,4) kept.
// Conv tile body verbatim r18/r25. absmax expected 0.00390625.

typedef _Float16 f16;
typedef _Float16 f16x8 __attribute__((ext_vector_type(8)));
typedef float    f32x4 __attribute__((ext_vector_type(4)));

#define WSTRIDE 442368   // fp32 weight elements per layer: 27*64*256
#define WPT     884736   // halfs per packed tensor: 54*256*64
#define XSP     65536    // halfs per s-slab of h: 512*128
#define HSP     458752   // halfs per nc of h: 7*512*128
#define GPART   262144   // floats per conv partial buffer: 2*512*256

__device__ __forceinline__ float wred_sum(float v) {
    #pragma unroll
    for (int o = 32; o > 0; o >>= 1) v += __shfl_down(v, o, 64);
    return __shfl(v, 0, 64);
}
__device__ __forceinline__ float fsig(float x)  { return 1.f / (1.f + __expf(-x)); }
__device__ __forceinline__ float ftanh(float x) { return 1.f - 2.f / (__expf(2.f*x) + 1.f); }

// prep: blocks [0,1792) embed h1 hi/lo; blocks [1792,1900) pack weights.
__global__ __launch_bounds__(256) void prep_kernel(
    const int* __restrict__ code, const int* __restrict__ ncode,
    const float* __restrict__ emb, f16* __restrict__ h,
    const float* __restrict__ win, const float* __restrict__ wh,
    f16* __restrict__ wp)
{
    if (blockIdx.x < 1792) {
        int e = blockIdx.x * 256 + threadIdx.x;   // < 458752
        int ch = e & 63;
        int pos = e >> 6;            // nc*7*512 + s*512 + vox
        int vox = pos & 511;
        int t = pos >> 9;
        int s = t % 7, nc = t / 7;
        int tok = (s < 5) ? code[(nc*5 + s)*512 + vox]
                          : ncode[(nc*3 + (s-5))*512 + vox];
        float x = emb[tok*64 + ch];
        f16 hi = (f16)x;
        h[(size_t)pos*128 + ch]      = hi;
        h[(size_t)pos*128 + 64 + ch] = (f16)(x - (float)hi);
    } else {
        // pack: src [27][64 ci][256 co] fp32 -> per K-atom (tap, ci-half)
        // [54][256 co][8 chunks][8] f16; hi chunk j at (j ^ (co&7)), lo at
        // ((4+j) ^ (co&7)); values x64. Order: win0, wh0, win1, wh1.
        int b = blockIdx.x - 1792;        // 108 = 4 tensors * 27 taps
        int tensor = b / 27, tap = b % 27;
        const float* src = ((tensor & 1) ? wh : win) + (tensor >> 1) * WSTRIDE
                         + tap * 16384;
        int co = threadIdx.x;
        int sw = co & 7;
        #pragma unroll
        for (int hs = 0; hs < 2; ++hs) {
            f16* dst = wp + (((size_t)tensor*27 + tap)*2 + hs)*16384 + co*64;
            #pragma unroll
            for (int j = 0; j < 4; ++j) {
                f16x8 hi8, lo8;
                #pragma unroll
                for (int m = 0; m < 8; ++m) {
                    float w = src[(hs*32 + j*8 + m)*256 + co] * 64.f;
                    f16 hv = (f16)w;
                    hi8[m] = hv;
                    lo8[m] = (f16)(w - (float)hv);
                }
                *(f16x8*)(dst + ((j     ^ sw))*8) = hi8;
                *(f16x8*)(dst + (((4+j) ^ sw))*8) = lo8;
            }
        }
    }
}

struct MJob { const f16* x; const f16* w; float* y; };
struct MJobs { MJob j[8]; };

// One 3x3x3 SAME conv job (Cin=64 -> Cout=256), implicit GEMM, 3-segment
// hi/lo f16 MFMA. grid.x = 512/job: [kb(4)|ah(2)|slab(2)|u(8)|cog(4)].
// Block = 32-vox a-half x 64 co; 54 K-atoms split over 16 groups (kb*4+wid:
// groups 0-5 have 4 atoms, 6-15 have 3). Each wave stages its atom tile
// (8KB, single-buffered) into a private region. One barrier; in-block 4-way
// K-reduce; partial written to y + kb*GPART (no bias).
__global__ __launch_bounds__(256, 4) void conv_mfma_kernel(MJobs js)
{
    const MJob J = js.j[blockIdx.y];
    __shared__ float4 smem[2048];          // 32 KiB
    f16* wbuf = (f16*)smem;

    const int bx = blockIdx.x;
    const int cog = bx & 3, u = (bx >> 2) & 7, slab = (bx >> 5) & 1;
    const int ah = (bx >> 6) & 1, kb = bx >> 7;       // kb in [0,4)
    const int t = threadIdx.x, wid = t >> 6, l = t & 63;
    const int lv = (l >> 3) & 1, lw = l & 7, khi = l >> 4;

    const int gid = kb*4 + wid;                       // 16 K-groups
    const int g0  = (gid < 6) ? gid*4 : 24 + (gid - 6)*3;
    const int cnt = (gid < 6) ? 4 : 3;

    const f16* xbase = J.x + (size_t)slab * HSP;
    const f16* wjob  = J.w + (size_t)cog * 4096;      // + atom*16384
    f16* wmine = wbuf + wid * 4096;                   // 8KB, single-buffered

    f16x8 wreg[8];
    auto wload = [&](int k) {
        const f16* src = wjob + (size_t)k * 16384 + l * 8;
        #pragma unroll
        for (int i = 0; i < 8; ++i) wreg[i] = *(const f16x8*)(src + i * 512);
    };
    auto wstore = [&]() {
        f16* dst = wmine + l * 8;
        #pragma unroll
        for (int i = 0; i < 8; ++i) *(f16x8*)(dst + i * 512) = wreg[i];
    };

    wload(g0); wstore();

    f32x4 acc[2][4] = {};
    for (int q = 0; q < cnt; ++q) {
        const int k = g0 + q;
        if (q + 1 < cnt) wload(k + 1);
        const int tap = k >> 1, hs = k & 1;
        const int du = tap / 9, rr = tap % 9, dv = rr / 3, dw = rr % 3;
        const int uu = u + du - 1;
        const bool uok = (unsigned)uu < 8u;
        const f16* xrow[2]; bool ok[2];
        #pragma unroll
        for (int aa = 0; aa < 2; ++aa) {
            int vs = (ah*2 + aa)*2 + lv + dv - 1, ws = lw + dw - 1;
            ok[aa] = uok && (unsigned)vs < 8u && (unsigned)ws < 8u;
            xrow[aa] = xbase + ((size_t)(uu*64 + vs*8 + ws) << 7) + khi*8;
        }
        const f16* wrow = wmine + (l & 15)*64;
        const int schi = ((khi    ) ^ lw) * 8;
        const int sclo = ((4 + khi) ^ lw) * 8;
        f16x8 ahi[2], alo[2], bhi[4], blo[4];
        #pragma unroll
        for (int aa = 0; aa < 2; ++aa) {
            f16x8 v = {0,0,0,0,0,0,0,0}, v2 = v;
            if (ok[aa]) {
                v  = *(const f16x8*)(xrow[aa] + hs*32);
                v2 = *(const f16x8*)(xrow[aa] + 64 + hs*32);
            }
            ahi[aa] = v; alo[aa] = v2;
        }
        #pragma unroll
        for (int n = 0; n < 4; ++n) {
            bhi[n] = *(const f16x8*)(wrow + n*1024 + schi);
            blo[n] = *(const f16x8*)(wrow + n*1024 + sclo);
        }
        #pragma unroll
        for (int aa = 0; aa < 2; ++aa)
            #pragma unroll
            for (int n = 0; n < 4; ++n)
                acc[aa][n] = __builtin_amdgcn_mfma_f32_16x16x32_f16(
                    ahi[aa], bhi[n], acc[aa][n], 0, 0, 0);
        #pragma unroll
        for (int aa = 0; aa < 2; ++aa)
            #pragma unroll
            for (int n = 0; n < 4; ++n)
                acc[aa][n] = __builtin_amdgcn_mfma_f32_16x16x32_f16(
                    alo[aa], bhi[n], acc[aa][n], 0, 0, 0);
        #pragma unroll
        for (int aa = 0; aa < 2; ++aa)
            #pragma unroll
            for (int n = 0; n < 4; ++n)
                acc[aa][n] = __builtin_amdgcn_mfma_f32_16x16x32_f16(
                    ahi[aa], blo[n], acc[aa][n], 0, 0, 0);
        if (q + 1 < cnt) wstore();
    }

    f32x4* red = (f32x4*)smem;
    {
        f32x4* mine = red + (size_t)(wid * 64 + l) * 8;
        #pragma unroll
        for (int aa = 0; aa < 2; ++aa)
            #pragma unroll
            for (int n = 0; n < 4; ++n)
                mine[(aa * 4 + n) ^ lw] = acc[aa][n];
    }
    __syncthreads();
    {
        float* yp = J.y + (size_t)kb * GPART;
        const int aa = (t >> 7) & 1, nsel = (t >> 6) & 1, ll = t & 63;
        #pragma unroll
        for (int ni = 0; ni < 2; ++ni) {
            const int n = nsel*2 + ni;
            const int ch = (aa * 4 + n) ^ (ll & 7);
            f32x4 sv = red[(0 * 64 + ll) * 8 + ch]
                     + red[(1 * 64 + ll) * 8 + ch]
                     + red[(2 * 64 + ll) * 8 + ch]
                     + red[(3 * 64 + ll) * 8 + ch];
            const int co = cog * 64 + n * 16 + (ll & 15);
            #pragma unroll
            for (int r = 0; r < 4; ++r) {
                int vox = (ah*2 + aa) * 16 + (ll >> 4) * 4 + r;
                yp[(size_t)(slab * 512 + u * 64 + vox) * 256 + co]
                    = sv[r] * 0.015625f;            // /64 (w' scale)
            }
        }
    }
}

// Dual-LN LSTM cell (fp32). Sums FOUR conv partials + bias per path.
// [r23 version, proven]
struct GJob {
    const float* gi;   // 4 partials at stride GPART
    const float* gh;   // 4 partials at stride GPART (ignored if k0)
    const float* bin; const float* bhb;
    const float* ginw; const float* ginb;
    const float* ghw;  const float* ghb;
    float* cx; f16* h16; int k; int k0;
};
__global__ __launch_bounds__(256) void gates_step_kernel(GJob ja, GJob jb)
{
    const GJob J = (blockIdx.y == 0) ? ja : jb;
    const int wid = threadIdx.x >> 6, lane = threadIdx.x & 63;
    const int row = blockIdx.x * 4 + wid;     // nc*512 + vox, < 1024
    const int nc = row >> 9, vox = row & 511;

    const float* g = J.gi + (size_t)row*256;
    float a0 = g[lane]             + g[GPART+lane]
             + g[2*GPART+lane]     + g[3*GPART+lane]     + J.bin[lane];
    float a1 = g[64+lane]          + g[GPART+64+lane]
             + g[2*GPART+64+lane]  + g[3*GPART+64+lane]  + J.bin[64+lane];
    float a2 = g[128+lane]         + g[GPART+128+lane]
             + g[2*GPART+128+lane] + g[3*GPART+128+lane] + J.bin[128+lane];
    float a3 = g[192+lane]         + g[GPART+192+lane]
             + g[2*GPART+192+lane] + g[3*GPART+192+lane] + J.bin[192+lane];
    float mu1 = wred_sum(a0+a1+a2+a3) * (1.f/256.f);
    float d0=a0-mu1, d1=a1-mu1, d2=a2-mu1, d3=a3-mu1;
    float v1 = wred_sum(d0*d0+d1*d1+d2*d2+d3*d3) * (1.f/256.f);
    float rs1 = rsqrtf(v1 + 1e-5f);

    float b0, b1, b2, b3;
    if (J.k0) {
        b0 = J.bhb[lane]; b1 = J.bhb[64+lane];
        b2 = J.bhb[128+lane]; b3 = J.bhb[192+lane];
    } else {
        const float* hh = J.gh + (size_t)row*256;
        b0 = hh[lane]             + hh[GPART+lane]
           + hh[2*GPART+lane]     + hh[3*GPART+lane]     + J.bhb[lane];
        b1 = hh[64+lane]          + hh[GPART+64+lane]
           + hh[2*GPART+64+lane]  + hh[3*GPART+64+lane]  + J.bhb[64+lane];
        b2 = hh[128+lane]         + hh[GPART+128+lane]
           + hh[2*GPART+128+lane] + hh[3*GPART+128+lane] + J.bhb[128+lane];
        b3 = hh[192+lane]         + hh[GPART+192+lane]
           + hh[2*GPART+192+lane] + hh[3*GPART+192+lane] + J.bhb[192+lane];
    }
    float mu2 = wred_sum(b0+b1+b2+b3) * (1.f/256.f);
    float e0=b0-mu2, e1=b1-mu2, e2=b2-mu2, e3=b3-mu2;
    float v2 = wred_sum(e0*e0+e1*e1+e2*e2+e3*e3) * (1.f/256.f);
    float rs2 = rsqrtf(v2 + 1e-5f);

    float Ig = d0*rs1*J.ginw[lane]     + J.ginb[lane]     + e0*rs2*J.ghw[lane]     + J.ghb[lane];
    float Fg = d1*rs1*J.ginw[64+lane]  + J.ginb[64+lane]  + e1*rs2*J.ghw[64+lane]  + J.ghb[64+lane];
    float Cg = d2*rs1*J.ginw[128+lane] + J.ginb[128+lane] + e2*rs2*J.ghw[128+lane] + J.ghb[128+lane];
    float Og = d3*rs1*J.ginw[192+lane] + J.ginb[192+lane] + e3*rs2*J.ghw[192+lane] + J.ghb[192+lane];

    float c_old = J.k0 ? 0.f : J.cx[(size_t)row*64 + lane];
    float c_new = fsig(Fg)*c_old + fsig(Ig)*ftanh(Cg);
    float h_new = fsig(Og)*ftanh(c_new);
    J.cx[(size_t)row*64 + lane] = c_new;
    size_t hb = ((size_t)(nc*7 + J.k)*512 + vox)*128 + lane;
    f16 hi = (f16)h_new;
    J.h16[hb]      = hi;
    J.h16[hb + 64] = (f16)(h_new - (float)hi);
}

// Head: 768 blocks x 4 vox (1 vox per wave). sn==2 blocks compute the
// slot-6 gates2 row INLINE (4-partial sums; h2/cx2 writes dead).
__global__ __launch_bounds__(256) void head_kernel(
    const f16* __restrict__ h,        // [2][7][512][128] hi/lo
    const float* __restrict__ w1, const float* __restrict__ b1,
    const float* __restrict__ lng, const float* __restrict__ lnb,
    const float* __restrict__ w2, const float* __restrict__ b2,
    const int* __restrict__ ncode,
    float* __restrict__ out, float* __restrict__ lossb, GJob g2)
{
    __shared__ float hsm[4][64];
    __shared__ float zv[4][64];
    __shared__ float lg[4][512];
    __shared__ float lsum[4];
    const int blk = blockIdx.x;               // 768 = n(2) x sn(3) x vg(128)
    const int n = blk / 384;
    const int sn = (blk / 128) % 3;
    const int vox0 = (blk & 127) * 4;
    const int t = threadIdx.x, wid = t >> 6, lane = t & 63;
    const int vox = vox0 + wid;

    if (sn == 2) {
        const int row = n*512 + vox;
        const float* g = g2.gi + (size_t)row*256;
        float a0 = g[lane]             + g[GPART+lane]
                 + g[2*GPART+lane]     + g[3*GPART+lane]     + g2.bin[lane];
        float a1 = g[64+lane]          + g[GPART+64+lane]
                 + g[2*GPART+64+lane]  + g[3*GPART+64+lane]  + g2.bin[64+lane];
        float a2 = g[128+lane]         + g[GPART+128+lane]
                 + g[2*GPART+128+lane] + g[3*GPART+128+lane] + g2.bin[128+lane];
        float a3 = g[192+lane]         + g[GPART+192+lane]
                 + g[2*GPART+192+lane] + g[3*GPART+192+lane] + g2.bin[192+lane];
        float mu1 = wred_sum(a0+a1+a2+a3) * (1.f/256.f);
        float d0=a0-mu1, d1=a1-mu1, d2=a2-mu1, d3=a3-mu1;
        float v1 = wred_sum(d0*d0+d1*d1+d2*d2+d3*d3) * (1.f/256.f);
        float rs1 = rsqrtf(v1 + 1e-5f);

        const float* hh = g2.gh + (size_t)row*256;
        float b0v = hh[lane]             + hh[GPART+lane]
                  + hh[2*GPART+lane]     + hh[3*GPART+lane]     + g2.bhb[lane];
        float b1v = hh[64+lane]          + hh[GPART+64+lane]
                  + hh[2*GPART+64+lane]  + hh[3*GPART+64+lane]  + g2.bhb[64+lane];
        float b2v = hh[128+lane]         + hh[GPART+128+lane]
                  + hh[2*GPART+128+lane] + hh[3*GPART+128+lane] + g2.bhb[128+lane];
        float b3v = hh[192+lane]         + hh[GPART+192+lane]
                  + hh[2*GPART+192+lane] + hh[3*GPART+192+lane] + g2.bhb[192+lane];
        float mu2 = wred_sum(b0v+b1v+b2v+b3v) * (1.f/256.f);
        float e0=b0v-mu2, e1=b1v-mu2, e2=b2v-mu2, e3=b3v-mu2;
        float v2 = wred_sum(e0*e0+e1*e1+e2*e2+e3*e3) * (1.f/256.f);
        float rs2 = rsqrtf(v2 + 1e-5f);

        float Ig = d0*rs1*g2.ginw[lane]     + g2.ginb[lane]     + e0*rs2*g2.ghw[lane]     + g2.ghb[lane];
        float Fg = d1*rs1*g2.ginw[64+lane]  + g2.ginb[64+lane]  + e1*rs2*g2.ghw[64+lane]  + g2.ghb[64+lane];
        float Cg = d2*rs1*g2.ginw[128+lane] + g2.ginb[128+lane] + e2*rs2*g2.ghw[128+lane] + g2.ghb[128+lane];
        float Og = d3*rs1*g2.ginw[192+lane] + g2.ginb[192+lane] + e3*rs2*g2.ghw[192+lane] + g2.ghb[192+lane];

        float c_old = g2.cx[(size_t)row*64 + lane];
        float c_new = fsig(Fg)*c_old + fsig(Ig)*ftanh(Cg);
        hsm[wid][lane] = fsig(Og)*ftanh(c_new);
    } else {
        const f16* hv = h + (size_t)((n*7 + sn + 4)*512 + vox)*128;
        hsm[wid][lane] = (float)hv[lane] + (float)hv[64 + lane];
    }

    // GEMV1 (h @ w1 + b1), dual accumulators
    float yva = b1[lane], yvb = 0.f;
    for (int kk = 0; kk < 64; kk += 2) {
        yva = fmaf(hsm[wid][kk],     w1[kk*64 + lane],     yva);
        yvb = fmaf(hsm[wid][kk + 1], w1[(kk+1)*64 + lane], yvb);
    }
    float yv = yva + yvb;
    float mu = wred_sum(yv) * (1.f/64.f);
    float d = yv - mu;
    float var = wred_sum(d*d) * (1.f/64.f);
    float ln = d * rsqrtf(var + 1e-5f) * lng[lane] + lnb[lane];
    zv[wid][lane] = 0.5f * ln * (1.f + erff(ln * 0.70710678118654752f));

    // GEMM2: logits[512] for this wave's vox; 8 independent chains
    float l[8];
    #pragma unroll
    for (int j = 0; j < 8; ++j) l[j] = b2[j*64 + lane];
    for (int kk = 0; kk < 64; ++kk) {
        float zz = zv[wid][kk];
        #pragma unroll
        for (int j = 0; j < 8; ++j)
            l[j] = fmaf(zz, w2[kk*512 + j*64 + lane], l[j]);
    }
    #pragma unroll
    for (int j = 0; j < 8; ++j) lg[wid][j*64 + lane] = l[j];

    // softmax / argmax / loss (wave-local)
    float m = l[0]; int mi = lane;
    #pragma unroll
    for (int j = 1; j < 8; ++j)
        if (l[j] > m) { m = l[j]; mi = j*64 + lane; }
    #pragma unroll
    for (int o = 32; o > 0; o >>= 1) {
        float om = __shfl_down(m, o, 64);
        int   oi = __shfl_down(mi, o, 64);
        if (om > m || (om == m && oi < mi)) { m = om; mi = oi; }
    }
    float maxv = __shfl(m, 0, 64);
    int   maxi = __shfl(mi, 0, 64);
    float es = 0.f;
    #pragma unroll
    for (int j = 0; j < 8; ++j) es += __expf(l[j] - maxv);
    float sum = wred_sum(es);
    if (lane == 0) {
        int target = ncode[(n*3 + sn)*512 + vox];
        float logp = lg[wid][target] - maxv - __logf(sum);
        lsum[wid] = -logp * (1.f/3072.f);
        out[1572865 + (n*3 + sn)*512 + vox] = (float)maxi;
    }

    __syncthreads();
    if (t == 0) lossb[blk] = lsum[0] + lsum[1] + lsum[2] + lsum[3];
    for (int co = t; co < 512; co += 256) {
        float4 o4 = { lg[0][co], lg[1][co], lg[2][co], lg[3][co] };
        *(float4*)(out + (size_t)((n*512 + co)*3 + sn)*512 + vox0) = o4;
    }
}

__global__ void loss_fin_kernel(const float* __restrict__ lossb,
                                float* __restrict__ out)
{
    float s = 0.f;
    for (int i = threadIdx.x; i < 768; i += 64) s += lossb[i];
    s = wred_sum(s);
    if (threadIdx.x == 0) out[1572864] = s;
}

extern "C" void kernel_launch(void* const* d_in, const int* in_sizes, int n_in,
                              void* d_out, int out_size, void* d_ws, size_t ws_size,
                              hipStream_t stream) {
    (void)in_sizes; (void)n_in; (void)out_size; (void)ws_size;
    const int*   code  = (const int*)d_in[0];
    const int*   ncode = (const int*)d_in[1];
    const float* emb   = (const float*)d_in[2];
    const float* win   = (const float*)d_in[3];
    const float* bin_  = (const float*)d_in[4];
    const float* gin_w = (const float*)d_in[5];
    const float* gin_b = (const float*)d_in[6];
    const float* wh    = (const float*)d_in[7];
    const float* bh    = (const float*)d_in[8];
    const float* gh_w  = (const float*)d_in[9];
    const float* gh_b  = (const float*)d_in[10];
    const float* w1    = (const float*)d_in[11];
    const float* b1    = (const float*)d_in[12];
    const float* ln_g  = (const float*)d_in[13];
    const float* ln_b  = (const float*)d_in[14];
    const float* w2    = (const float*)d_in[15];
    const float* b2    = (const float*)d_in[16];
    float* out = (float*)d_out;

    float* base  = (float*)d_ws;
    f16*   wp    = (f16*)base;                    // 1,769,472 floats
    f16*   h1    = (f16*)(base + 1769472);        // 458,752 floats
    f16*   h2    = (f16*)(base + 2228224);        // 458,752 floats
    float* gi1   = base + 2686976;                // 7 slots x 4 partials
    float* gi2   = gi1 + 7*4*(size_t)GPART;       // base + 10,027,008
    float* ghat1 = gi2 + 4*(size_t)GPART;         // base + 11,075,584
    float* ghat2 = ghat1 + 4*(size_t)GPART;       // base + 12,124,160
    float* cx1   = ghat2 + 4*(size_t)GPART;       // base + 13,172,736
    float* cx2   = cx1 + 65536;                   // base + 13,238,272
    float* lossb = base + 13303808;               // 768 floats (~53.2 MB end)

    const f16* win0 = wp;
    const f16* wh0  = wp + WPT;
    const f16* win1 = wp + 2*WPT;
    const f16* wh1  = wp + 3*WPT;

    prep_kernel<<<1900, 256, 0, stream>>>(code, ncode, emb, h1, win, wh, wp);

    // all 7 recurrence-free layer-1 input convs, one batched dispatch
    {
        MJobs js{};
        for (int s = 0; s < 7; ++s)
            js.j[s] = { h1 + (size_t)s*XSP, win0, gi1 + (size_t)s*4*GPART };
        conv_mfma_kernel<<<dim3(512, 7), 256, 0, stream>>>(js);
    }

    for (int s = 0; s <= 6; ++s) {
        // ---- gates: gates1(s); gates2(s-1) if s>=1 ----
        GJob g1 = { gi1 + (size_t)s*4*GPART, ghat1, bin_, bh,
                    gin_w, gin_b, gh_w, gh_b, cx1, h1, s, s == 0 };
        GJob g2 = { gi2, ghat2, bin_ + 256, bh + 256,
                    gin_w + 256, gin_b + 256, gh_w + 256, gh_b + 256,
                    cx2, h2, s - 1, s == 1 };
        if (s == 0)
            gates_step_kernel<<<dim3(256, 1), 256, 0, stream>>>(g1, g1);
        else
            gates_step_kernel<<<dim3(256, 2), 256, 0, stream>>>(g1, g2);

        // ---- convs: rec1(s) [s<=5], in2(s), rec2(s-1) [s>=1] ----
        MJobs js{}; int nj = 0;
        if (s <= 5) js.j[nj++] = { h1 + (size_t)s*XSP,     wh0,  ghat1 };
        js.j[nj++]             = { h1 + (size_t)s*XSP,     win1, gi2 };
        if (s >= 1) js.j[nj++] = { h2 + (size_t)(s-1)*XSP, wh1,  ghat2 };
        conv_mfma_kernel<<<dim3(512, nj), 256, 0, stream>>>(js);
    }

    // head absorbs gates2(6)
    GJob g2h = { gi2, ghat2, bin_ + 256, bh + 256,
                 gin_w + 256, gin_b + 256, gh_w + 256, gh_b + 256,
                 cx2, h2, 6, 0 };
    head_kernel<<<768, 256, 0, stream>>>(h2, w1, b1, ln_g, ln_b, w2, b2,
                                         ncode, out, lossb, g2h);
    loss_fin_kernel<<<1, 64, 0, stream>>>(lossb, out);
}

// Round 13
// 279.312 us; speedup vs baseline: 1.1139x; 1.1139x over previous
//
#include <hip/hip_runtime.h>

// r27: X-layout fix. r26's counters (MfmaUtil 17%, VALUBusy 22%, HBM 11%,
// nothing saturated) indict the conv A-loads: h stored [vox][128] makes each
// lane's 16B read land 256B from its neighbor's -> 64 scattered lines per
// load from L2. New layout: h [slab][16 ci-chunk][512 vox][8 f16] -> a wave's
// A-load = 8 dense 128B segments (4x fewer lines, fully used). Producers
// (embed, gates) and head updated to match; values bit-identical.
// Base: r24 kb=2 conv/gates (305us proven) + r25 head-absorbed gates2(6).
// absmax expected 0.00390625.

typedef _Float16 f16;
typedef _Float16 f16x8 __attribute__((ext_vector_type(8)));
typedef float    f32x4 __attribute__((ext_vector_type(4)));

#define WSTRIDE 442368   // fp32 weight elements per layer: 27*64*256
#define WPT     884736   // halfs per packed tensor: 54*256*64
#define XSP     65536    // halfs per s-slab of h: 16*512*8
#define HSP     458752   // halfs per nc of h: 7*65536
#define GPART   262144   // floats per conv partial buffer: 2*512*256

__device__ __forceinline__ float wred_sum(float v) {
    #pragma unroll
    for (int o = 32; o > 0; o >>= 1) v += __shfl_down(v, o, 64);
    return __shfl(v, 0, 64);
}
__device__ __forceinline__ float fsig(float x)  { return 1.f / (1.f + __expf(-x)); }
__device__ __forceinline__ float ftanh(float x) { return 1.f - 2.f / (__expf(2.f*x) + 1.f); }

// prep: blocks [0,1792) embed h1 (chunk-major); [1792,1900) pack weights.
__global__ __launch_bounds__(256) void prep_kernel(
    const int* __restrict__ code, const int* __restrict__ ncode,
    const float* __restrict__ emb, f16* __restrict__ h,
    const float* __restrict__ win, const float* __restrict__ wh,
    f16* __restrict__ wp)
{
    if (blockIdx.x < 1792) {
        int e = blockIdx.x * 256 + threadIdx.x;   // < 458752
        int ch = e & 63;
        int pos = e >> 6;            // slab*512 + vox, slab = nc*7+s
        int vox = pos & 511;
        int slab = pos >> 9;
        int s = slab % 7, nc = slab / 7;
        int tok = (s < 5) ? code[(nc*5 + s)*512 + vox]
                          : ncode[(nc*3 + (s-5))*512 + vox];
        float x = emb[tok*64 + ch];
        f16 hi = (f16)x;
        size_t sb = (size_t)slab * XSP;
        h[sb + (ch>>3)*4096       + vox*8 + (ch&7)] = hi;
        h[sb + ((ch>>3)+8)*4096   + vox*8 + (ch&7)] = (f16)(x - (float)hi);
    } else {
        // pack: src [27][64 ci][256 co] fp32 -> per K-atom (tap, ci-half)
        // [54][256 co][8 chunks][8] f16; hi chunk j at (j ^ (co&7)), lo at
        // ((4+j) ^ (co&7)); values x64. Order: win0, wh0, win1, wh1.
        int b = blockIdx.x - 1792;        // 108 = 4 tensors * 27 taps
        int tensor = b / 27, tap = b % 27;
        const float* src = ((tensor & 1) ? wh : win) + (tensor >> 1) * WSTRIDE
                         + tap * 16384;
        int co = threadIdx.x;
        int sw = co & 7;
        #pragma unroll
        for (int hs = 0; hs < 2; ++hs) {
            f16* dst = wp + (((size_t)tensor*27 + tap)*2 + hs)*16384 + co*64;
            #pragma unroll
            for (int j = 0; j < 4; ++j) {
                f16x8 hi8, lo8;
                #pragma unroll
                for (int m = 0; m < 8; ++m) {
                    float w = src[(hs*32 + j*8 + m)*256 + co] * 64.f;
                    f16 hv = (f16)w;
                    hi8[m] = hv;
                    lo8[m] = (f16)(w - (float)hv);
                }
                *(f16x8*)(dst + ((j     ^ sw))*8) = hi8;
                *(f16x8*)(dst + (((4+j) ^ sw))*8) = lo8;
            }
        }
    }
}

struct MJob { const f16* x; const f16* w; float* y; };
struct MJobs { MJob j[8]; };

// One 3x3x3 SAME conv job (Cin=64 -> Cout=256), implicit GEMM, 3-segment
// hi/lo f16 MFMA. grid.x = 256/job: [kb(2)|ah(2)|slab(2)|u(8)|cog(4)].
// Block = 32-vox a-half x 64 co; 54 K-atoms over 8 groups (kb*4+wid,
// {7x6,6x2}); waves stage their atom's W tile (8KB) in private LDS.
// X read chunk-major: lane addr = chunk*4096 + vox*8 (8 dense 128B
// segments per wave-load). Partial -> y + kb*GPART.
__global__ __launch_bounds__(256, 4) void conv_mfma_kernel(MJobs js)
{
    const MJob J = js.j[blockIdx.y];
    __shared__ float4 smem[2048];          // 32 KiB
    f16* wbuf = (f16*)smem;

    const int bx = blockIdx.x;
    const int cog = bx & 3, u = (bx >> 2) & 7, slab = (bx >> 5) & 1;
    const int ah = (bx >> 6) & 1, kb = bx >> 7;
    const int t = threadIdx.x, wid = t >> 6, l = t & 63;
    const int lv = (l >> 3) & 1, lw = l & 7, khi = l >> 4;

    const int gid = kb*4 + wid;
    const int g0  = (gid < 6) ? gid*7 : 42 + (gid - 6)*6;
    const int cnt = (gid < 6) ? 7 : 6;

    const f16* xbase = J.x + (size_t)slab * HSP;
    const f16* wjob  = J.w + (size_t)cog * 4096;      // + atom*16384
    f16* wmine = wbuf + wid * 4096;                   // 8KB, single-buffered

    f16x8 wreg[8];
    auto wload = [&](int k) {
        const f16* src = wjob + (size_t)k * 16384 + l * 8;
        #pragma unroll
        for (int i = 0; i < 8; ++i) wreg[i] = *(const f16x8*)(src + i * 512);
    };
    auto wstore = [&]() {
        f16* dst = wmine + l * 8;
        #pragma unroll
        for (int i = 0; i < 8; ++i) *(f16x8*)(dst + i * 512) = wreg[i];
    };

    wload(g0); wstore();

    f32x4 acc[2][4] = {};
    for (int q = 0; q < cnt; ++q) {
        const int k = g0 + q;
        if (q + 1 < cnt) wload(k + 1);
        const int tap = k >> 1, hs = k & 1;
        const int du = tap / 9, rr = tap % 9, dv = rr / 3, dw = rr % 3;
        const int uu = u + du - 1;
        const bool uok = (unsigned)uu < 8u;
        const int choff = (khi + hs*4) * 4096;      // hi chunk; lo = +32768
        const f16* xrow[2]; bool ok[2];
        #pragma unroll
        for (int aa = 0; aa < 2; ++aa) {
            int vs = (ah*2 + aa)*2 + lv + dv - 1, ws = lw + dw - 1;
            ok[aa] = uok && (unsigned)vs < 8u && (unsigned)ws < 8u;
            xrow[aa] = xbase + choff + (uu*64 + vs*8 + ws)*8;
        }
        const f16* wrow = wmine + (l & 15)*64;
        const int schi = ((khi    ) ^ lw) * 8;
        const int sclo = ((4 + khi) ^ lw) * 8;
        f16x8 ahi[2], alo[2], bhi[4], blo[4];
        #pragma unroll
        for (int aa = 0; aa < 2; ++aa) {
            f16x8 v = {0,0,0,0,0,0,0,0}, v2 = v;
            if (ok[aa]) {
                v  = *(const f16x8*)(xrow[aa]);
                v2 = *(const f16x8*)(xrow[aa] + 32768);
            }
            ahi[aa] = v; alo[aa] = v2;
        }
        #pragma unroll
        for (int n = 0; n < 4; ++n) {
            bhi[n] = *(const f16x8*)(wrow + n*1024 + schi);
            blo[n] = *(const f16x8*)(wrow + n*1024 + sclo);
        }
        #pragma unroll
        for (int aa = 0; aa < 2; ++aa)
            #pragma unroll
            for (int n = 0; n < 4; ++n)
                acc[aa][n] = __builtin_amdgcn_mfma_f32_16x16x32_f16(
                    ahi[aa], bhi[n], acc[aa][n], 0, 0, 0);
        #pragma unroll
        for (int aa = 0; aa < 2; ++aa)
            #pragma unroll
            for (int n = 0; n < 4; ++n)
                acc[aa][n] = __builtin_amdgcn_mfma_f32_16x16x32_f16(
                    alo[aa], bhi[n], acc[aa][n], 0, 0, 0);
        #pragma unroll
        for (int aa = 0; aa < 2; ++aa)
            #pragma unroll
            for (int n = 0; n < 4; ++n)
                acc[aa][n] = __builtin_amdgcn_mfma_f32_16x16x32_f16(
                    ahi[aa], blo[n], acc[aa][n], 0, 0, 0);
        if (q + 1 < cnt) wstore();
    }

    f32x4* red = (f32x4*)smem;
    {
        f32x4* mine = red + (size_t)(wid * 64 + l) * 8;
        #pragma unroll
        for (int aa = 0; aa < 2; ++aa)
            #pragma unroll
            for (int n = 0; n < 4; ++n)
                mine[(aa * 4 + n) ^ lw] = acc[aa][n];
    }
    __syncthreads();
    {
        float* yp = J.y + (size_t)kb * GPART;
        const int aa = (t >> 7) & 1, nsel = (t >> 6) & 1, ll = t & 63;
        #pragma unroll
        for (int ni = 0; ni < 2; ++ni) {
            const int n = nsel*2 + ni;
            const int ch = (aa * 4 + n) ^ (ll & 7);
            f32x4 sv = red[(0 * 64 + ll) * 8 + ch]
                     + red[(1 * 64 + ll) * 8 + ch]
                     + red[(2 * 64 + ll) * 8 + ch]
                     + red[(3 * 64 + ll) * 8 + ch];
            const int co = cog * 64 + n * 16 + (ll & 15);
            #pragma unroll
            for (int r = 0; r < 4; ++r) {
                int vox = (ah*2 + aa) * 16 + (ll >> 4) * 4 + r;
                yp[(size_t)(slab * 512 + u * 64 + vox) * 256 + co]
                    = sv[r] * 0.015625f;            // /64 (w' scale)
            }
        }
    }
}

// Dual-LN LSTM cell (fp32). Sums the two conv partials + bias per path.
// h written chunk-major.
struct GJob {
    const float* giA; const float* giB;
    const float* ghA; const float* ghB;
    const float* bin; const float* bhb;
    const float* ginw; const float* ginb;
    const float* ghw;  const float* ghb;
    float* cx; f16* h16; int k; int k0;
};
__global__ __launch_bounds__(256) void gates_step_kernel(GJob ja, GJob jb)
{
    const GJob J = (blockIdx.y == 0) ? ja : jb;
    const int wid = threadIdx.x >> 6, lane = threadIdx.x & 63;
    const int row = blockIdx.x * 4 + wid;     // nc*512 + vox, < 1024
    const int nc = row >> 9, vox = row & 511;

    const float* gA = J.giA + (size_t)row*256;
    const float* gB = J.giB + (size_t)row*256;
    float a0 = gA[lane]     + gB[lane]     + J.bin[lane];
    float a1 = gA[64+lane]  + gB[64+lane]  + J.bin[64+lane];
    float a2 = gA[128+lane] + gB[128+lane] + J.bin[128+lane];
    float a3 = gA[192+lane] + gB[192+lane] + J.bin[192+lane];
    float mu1 = wred_sum(a0+a1+a2+a3) * (1.f/256.f);
    float d0=a0-mu1, d1=a1-mu1, d2=a2-mu1, d3=a3-mu1;
    float v1 = wred_sum(d0*d0+d1*d1+d2*d2+d3*d3) * (1.f/256.f);
    float rs1 = rsqrtf(v1 + 1e-5f);

    float b0, b1, b2, b3;
    if (J.k0) {
        b0 = J.bhb[lane]; b1 = J.bhb[64+lane];
        b2 = J.bhb[128+lane]; b3 = J.bhb[192+lane];
    } else {
        const float* hA = J.ghA + (size_t)row*256;
        const float* hB = J.ghB + (size_t)row*256;
        b0 = hA[lane]     + hB[lane]     + J.bhb[lane];
        b1 = hA[64+lane]  + hB[64+lane]  + J.bhb[64+lane];
        b2 = hA[128+lane] + hB[128+lane] + J.bhb[128+lane];
        b3 = hA[192+lane] + hB[192+lane] + J.bhb[192+lane];
    }
    float mu2 = wred_sum(b0+b1+b2+b3) * (1.f/256.f);
    float e0=b0-mu2, e1=b1-mu2, e2=b2-mu2, e3=b3-mu2;
    float v2 = wred_sum(e0*e0+e1*e1+e2*e2+e3*e3) * (1.f/256.f);
    float rs2 = rsqrtf(v2 + 1e-5f);

    float Ig = d0*rs1*J.ginw[lane]     + J.ginb[lane]     + e0*rs2*J.ghw[lane]     + J.ghb[lane];
    float Fg = d1*rs1*J.ginw[64+lane]  + J.ginb[64+lane]  + e1*rs2*J.ghw[64+lane]  + J.ghb[64+lane];
    float Cg = d2*rs1*J.ginw[128+lane] + J.ginb[128+lane] + e2*rs2*J.ghw[128+lane] + J.ghb[128+lane];
    float Og = d3*rs1*J.ginw[192+lane] + J.ginb[192+lane] + e3*rs2*J.ghw[192+lane] + J.ghb[192+lane];

    float c_old = J.k0 ? 0.f : J.cx[(size_t)row*64 + lane];
    float c_new = fsig(Fg)*c_old + fsig(Ig)*ftanh(Cg);
    float h_new = fsig(Og)*ftanh(c_new);
    J.cx[(size_t)row*64 + lane] = c_new;
    size_t sb = (size_t)(nc*7 + J.k) * XSP;
    f16 hi = (f16)h_new;
    J.h16[sb + (lane>>3)*4096     + vox*8 + (lane&7)] = hi;
    J.h16[sb + ((lane>>3)+8)*4096 + vox*8 + (lane&7)] = (f16)(h_new - (float)hi);
}

// Head: 768 blocks x 4 vox (1 vox per wave). sn==2 blocks compute the
// slot-6 gates2 row INLINE (2-partial sums). Chunk-major h read.
__global__ __launch_bounds__(256) void head_kernel(
    const f16* __restrict__ h,        // [2][7][16][512][8] hi/lo chunk-major
    const float* __restrict__ w1, const float* __restrict__ b1,
    const float* __restrict__ lng, const float* __restrict__ lnb,
    const float* __restrict__ w2, const float* __restrict__ b2,
    const int* __restrict__ ncode,
    float* __restrict__ out, float* __restrict__ lossb, GJob g2)
{
    __shared__ float hsm[4][64];
    __shared__ float zv[4][64];
    __shared__ float lg[4][512];
    __shared__ float lsum[4];
    const int blk = blockIdx.x;               // 768 = n(2) x sn(3) x vg(128)
    const int n = blk / 384;
    const int sn = (blk / 128) % 3;
    const int vox0 = (blk & 127) * 4;
    const int t = threadIdx.x, wid = t >> 6, lane = t & 63;
    const int vox = vox0 + wid;

    if (sn == 2) {
        const int row = n*512 + vox;
        const float* gA = g2.giA + (size_t)row*256;
        const float* gB = g2.giB + (size_t)row*256;
        float a0 = gA[lane]     + gB[lane]     + g2.bin[lane];
        float a1 = gA[64+lane]  + gB[64+lane]  + g2.bin[64+lane];
        float a2 = gA[128+lane] + gB[128+lane] + g2.bin[128+lane];
        float a3 = gA[192+lane] + gB[192+lane] + g2.bin[192+lane];
        float mu1 = wred_sum(a0+a1+a2+a3) * (1.f/256.f);
        float d0=a0-mu1, d1=a1-mu1, d2=a2-mu1, d3=a3-mu1;
        float v1 = wred_sum(d0*d0+d1*d1+d2*d2+d3*d3) * (1.f/256.f);
        float rs1 = rsqrtf(v1 + 1e-5f);

        const float* hA = g2.ghA + (size_t)row*256;
        const float* hB = g2.ghB + (size_t)row*256;
        float b0v = hA[lane]     + hB[lane]     + g2.bhb[lane];
        float b1v = hA[64+lane]  + hB[64+lane]  + g2.bhb[64+lane];
        float b2v = hA[128+lane] + hB[128+lane] + g2.bhb[128+lane];
        float b3v = hA[192+lane] + hB[192+lane] + g2.bhb[192+lane];
        float mu2 = wred_sum(b0v+b1v+b2v+b3v) * (1.f/256.f);
        float e0=b0v-mu2, e1=b1v-mu2, e2=b2v-mu2, e3=b3v-mu2;
        float v2 = wred_sum(e0*e0+e1*e1+e2*e2+e3*e3) * (1.f/256.f);
        float rs2 = rsqrtf(v2 + 1e-5f);

        float Ig = d0*rs1*g2.ginw[lane]     + g2.ginb[lane]     + e0*rs2*g2.ghw[lane]     + g2.ghb[lane];
        float Fg = d1*rs1*g2.ginw[64+lane]  + g2.ginb[64+lane]  + e1*rs2*g2.ghw[64+lane]  + g2.ghb[64+lane];
        float Cg = d2*rs1*g2.ginw[128+lane] + g2.ginb[128+lane] + e2*rs2*g2.ghw[128+lane] + g2.ghb[128+lane];
        float Og = d3*rs1*g2.ginw[192+lane] + g2.ginb[192+lane] + e3*rs2*g2.ghw[192+lane] + g2.ghb[192+lane];

        float c_old = g2.cx[(size_t)row*64 + lane];
        float c_new = fsig(Fg)*c_old + fsig(Ig)*ftanh(Cg);
        hsm[wid][lane] = fsig(Og)*ftanh(c_new);
    } else {
        const f16* hv = h + (size_t)(n*7 + sn + 4) * XSP;
        hsm[wid][lane] = (float)hv[(lane>>3)*4096     + vox*8 + (lane&7)]
                       + (float)hv[((lane>>3)+8)*4096 + vox*8 + (lane&7)];
    }

    // GEMV1 (h @ w1 + b1), dual accumulators
    float yva = b1[lane], yvb = 0.f;
    for (int kk = 0; kk < 64; kk += 2) {
        yva = fmaf(hsm[wid][kk],     w1[kk*64 + lane],     yva);
        yvb = fmaf(hsm[wid][kk + 1], w1[(kk+1)*64 + lane], yvb);
    }
    float yv = yva + yvb;
    float mu = wred_sum(yv) * (1.f/64.f);
    float d = yv - mu;
    float var = wred_sum(d*d) * (1.f/64.f);
    float ln = d * rsqrtf(var + 1e-5f) * lng[lane] + lnb[lane];
    zv[wid][lane] = 0.5f * ln * (1.f + erff(ln * 0.70710678118654752f));

    // GEMM2: logits[512] for this wave's vox; 8 independent chains
    float l[8];
    #pragma unroll
    for (int j = 0; j < 8; ++j) l[j] = b2[j*64 + lane];
    for (int kk = 0; kk < 64; ++kk) {
        float zz = zv[wid][kk];
        #pragma unroll
        for (int j = 0; j < 8; ++j)
            l[j] = fmaf(zz, w2[kk*512 + j*64 + lane], l[j]);
    }
    #pragma unroll
    for (int j = 0; j < 8; ++j) lg[wid][j*64 + lane] = l[j];

    // softmax / argmax / loss (wave-local)
    float m = l[0]; int mi = lane;
    #pragma unroll
    for (int j = 1; j < 8; ++j)
        if (l[j] > m) { m = l[j]; mi = j*64 + lane; }
    #pragma unroll
    for (int o = 32; o > 0; o >>= 1) {
        float om = __shfl_down(m, o, 64);
        int   oi = __shfl_down(mi, o, 64);
        if (om > m || (om == m && oi < mi)) { m = om; mi = oi; }
    }
    float maxv = __shfl(m, 0, 64);
    int   maxi = __shfl(mi, 0, 64);
    float es = 0.f;
    #pragma unroll
    for (int j = 0; j < 8; ++j) es += __expf(l[j] - maxv);
    float sum = wred_sum(es);
    if (lane == 0) {
        int target = ncode[(n*3 + sn)*512 + vox];
        float logp = lg[wid][target] - maxv - __logf(sum);
        lsum[wid] = -logp * (1.f/3072.f);
        out[1572865 + (n*3 + sn)*512 + vox] = (float)maxi;
    }

    __syncthreads();
    if (t == 0) lossb[blk] = lsum[0] + lsum[1] + lsum[2] + lsum[3];
    for (int co = t; co < 512; co += 256) {
        float4 o4 = { lg[0][co], lg[1][co], lg[2][co], lg[3][co] };
        *(float4*)(out + (size_t)((n*512 + co)*3 + sn)*512 + vox0) = o4;
    }
}

__global__ void loss_fin_kernel(const float* __restrict__ lossb,
                                float* __restrict__ out)
{
    float s = 0.f;
    for (int i = threadIdx.x; i < 768; i += 64) s += lossb[i];
    s = wred_sum(s);
    if (threadIdx.x == 0) out[1572864] = s;
}

extern "C" void kernel_launch(void* const* d_in, const int* in_sizes, int n_in,
                              void* d_out, int out_size, void* d_ws, size_t ws_size,
                              hipStream_t stream) {
    (void)in_sizes; (void)n_in; (void)out_size; (void)ws_size;
    const int*   code  = (const int*)d_in[0];
    const int*   ncode = (const int*)d_in[1];
    const float* emb   = (const float*)d_in[2];
    const float* win   = (const float*)d_in[3];
    const float* bin_  = (const float*)d_in[4];
    const float* gin_w = (const float*)d_in[5];
    const float* gin_b = (const float*)d_in[6];
    const float* wh    = (const float*)d_in[7];
    const float* bh    = (const float*)d_in[8];
    const float* gh_w  = (const float*)d_in[9];
    const float* gh_b  = (const float*)d_in[10];
    const float* w1    = (const float*)d_in[11];
    const float* b1    = (const float*)d_in[12];
    const float* ln_g  = (const float*)d_in[13];
    const float* ln_b  = (const float*)d_in[14];
    const float* w2    = (const float*)d_in[15];
    const float* b2    = (const float*)d_in[16];
    float* out = (float*)d_out;

    float* base  = (float*)d_ws;
    f16*   wp    = (f16*)base;                    // 1,769,472 floats
    f16*   h1    = (f16*)(base + 1769472);        // 458,752 floats
    f16*   h2    = (f16*)(base + 2228224);        // 458,752 floats
    float* gi1   = base + 2686976;                // 7 slots x 2 partials
    float* gi2   = gi1 + 7*2*(size_t)GPART;       // base + 6,356,992
    float* ghat1 = gi2 + 2*GPART;                 // base + 6,881,280
    float* ghat2 = ghat1 + 2*GPART;               // base + 7,405,568
    float* cx1   = ghat2 + 2*GPART;               // base + 7,929,856
    float* cx2   = cx1 + 65536;                   // base + 7,995,392
    float* lossb = base + 8060928;                // 768 floats

    const f16* win0 = wp;
    const f16* wh0  = wp + WPT;
    const f16* win1 = wp + 2*WPT;
    const f16* wh1  = wp + 3*WPT;

    prep_kernel<<<1900, 256, 0, stream>>>(code, ncode, emb, h1, win, wh, wp);

    // all 7 recurrence-free layer-1 input convs, one batched dispatch
    {
        MJobs js{};
        for (int s = 0; s < 7; ++s)
            js.j[s] = { h1 + (size_t)s*XSP, win0, gi1 + (size_t)s*2*GPART };
        conv_mfma_kernel<<<dim3(256, 7), 256, 0, stream>>>(js);
    }

    for (int s = 0; s <= 6; ++s) {
        // ---- gates: gates1(s); gates2(s-1) if s>=1 ----
        GJob g1 = { gi1 + (size_t)s*2*GPART, gi1 + (size_t)s*2*GPART + GPART,
                    ghat1, ghat1 + GPART, bin_, bh,
                    gin_w, gin_b, gh_w, gh_b, cx1, h1, s, s == 0 };
        GJob g2 = { gi2, gi2 + GPART, ghat2, ghat2 + GPART, bin_ + 256, bh + 256,
                    gin_w + 256, gin_b + 256, gh_w + 256, gh_b + 256,
                    cx2, h2, s - 1, s == 1 };
        if (s == 0)
            gates_step_kernel<<<dim3(256, 1), 256, 0, stream>>>(g1, g1);
        else
            gates_step_kernel<<<dim3(256, 2), 256, 0, stream>>>(g1, g2);

        // ---- convs: rec1(s) [s<=5], in2(s), rec2(s-1) [s>=1] ----
        MJobs js{}; int nj = 0;
        if (s <= 5) js.j[nj++] = { h1 + (size_t)s*XSP,     wh0,  ghat1 };
        js.j[nj++]             = { h1 + (size_t)s*XSP,     win1, gi2 };
        if (s >= 1) js.j[nj++] = { h2 + (size_t)(s-1)*XSP, wh1,  ghat2 };
        conv_mfma_kernel<<<dim3(256, nj), 256, 0, stream>>>(js);
    }

    // head absorbs gates2(6)
    GJob g2h = { gi2, gi2 + GPART, ghat2, ghat2 + GPART, bin_ + 256, bh + 256,
                 gin_w + 256, gin_b + 256, gh_w + 256, gh_b + 256,
                 cx2, h2, 6, 0 };
    head_kernel<<<768, 256, 0, stream>>>(h2, w1, b1, ln_g, ln_b, w2, b2,
                                         ncode, out, lossb, g2h);
    loss_fin_kernel<<<1, 64, 0, stream>>>(lossb, out);
}